// Round 19
// baseline (447.166 us; speedup 1.0000x reference)
//
#include <hip/hip_runtime.h>

#define NN 50000
#define NE 800000
#define HID 256
#define NCLS 40

typedef short bf16x8 __attribute__((ext_vector_type(8)));
typedef float f32x4 __attribute__((ext_vector_type(4)));

__device__ inline unsigned short f2bf(float f) {            // RNE float->bf16
    unsigned int u = __float_as_uint(f);
    return (unsigned short)((u + 0x7FFFu + ((u >> 16) & 1u)) >> 16);
}
__device__ inline unsigned int pack2bf(float a, float b) {
    return (unsigned int)f2bf(a) | ((unsigned int)f2bf(b) << 16);
}
__device__ inline float2 bf2x(unsigned int u) {             // 2 bf16 -> 2 f32
    return make_float2(__uint_as_float(u << 16), __uint_as_float(u & 0xFFFF0000u));
}

// ---------------- CSR build + degree histogram ----------------
__global__ void k_scanA(const int* __restrict__ counts, int* __restrict__ indptr,
                        int* __restrict__ bsum, int* __restrict__ dhist) {
    __shared__ int sh[256];
    int t = threadIdx.x;
    int idx = blockIdx.x * 256 + t;
    int c = idx < NN ? counts[idx] : 0;
    sh[t] = c;
    __syncthreads();
    for (int off = 1; off < 256; off <<= 1) {
        int v = (t >= off) ? sh[t - off] : 0;
        __syncthreads();
        sh[t] += v;
        __syncthreads();
    }
    if (idx < NN) {
        indptr[idx] = sh[t] - c;
        int b = c < 255 ? c : 255;
        atomicAdd(&dhist[b], 1);
    }
    if (t == 255) bsum[blockIdx.x] = sh[255];
}

// scan block sums AND degree histogram (both 256-wide, one block)
__global__ void k_scanB(int* __restrict__ bsum, int nb, int* __restrict__ dhist) {
    __shared__ int sh[256];
    int t = threadIdx.x;
    int c = t < nb ? bsum[t] : 0;
    sh[t] = c;
    __syncthreads();
    for (int off = 1; off < 256; off <<= 1) {
        int v = (t >= off) ? sh[t - off] : 0;
        __syncthreads();
        sh[t] += v;
        __syncthreads();
    }
    if (t < nb) bsum[t] = sh[t] - c;
    __syncthreads();
    int h = dhist[t];
    sh[t] = h;
    __syncthreads();
    for (int off = 1; off < 256; off <<= 1) {
        int v = (t >= off) ? sh[t - off] : 0;
        __syncthreads();
        sh[t] += v;
        __syncthreads();
    }
    dhist[t] = sh[t] - h;            // exclusive base per degree bin
}

// finalize indptr, zero fill, AND scatter degree-sorted permutation
__global__ void k_scanC(int* __restrict__ indptr, const int* __restrict__ bsum,
                        int* __restrict__ fill, const int* __restrict__ counts,
                        const int* __restrict__ dhist, int* __restrict__ dfill,
                        int* __restrict__ perm) {
    int idx = blockIdx.x * 256 + threadIdx.x;
    if (idx < NN) {
        indptr[idx] += bsum[idx >> 8];
        fill[idx] = 0;
        int c = counts[idx];
        int b = c < 255 ? c : 255;
        int pos = atomicAdd(&dfill[b], 1);
        perm[dhist[b] + pos] = idx;
    }
    if (idx == 0) indptr[NN] = NE;
}

// scatter + fused layer-1 edge weights (raw, unnormalized) in CSR order
__global__ void k_scatterw(const int* __restrict__ src, const int* __restrict__ dst,
                           const int* __restrict__ indptr, int* __restrict__ fill,
                           const float* __restrict__ el1, const float* __restrict__ er1,
                           int* __restrict__ srcs, float4* __restrict__ w4) {
    int e = blockIdx.x * 256 + threadIdx.x;
    if (e < NE) {
        int d = dst[e];
        int s = src[e];
        int pos = atomicAdd(&fill[d], 1);
        int j = indptr[d] + pos;
        srcs[j] = s;
        float4 ls = *(const float4*)&el1[(size_t)s * 4];
        float4 rd = *(const float4*)&er1[(size_t)d * 4];
        float e0 = ls.x + rd.x, e1 = ls.y + rd.y, e2 = ls.z + rd.z, e3 = ls.w + rd.w;
        e0 = e0 > 0.f ? e0 : 0.2f * e0;
        e1 = e1 > 0.f ? e1 : 0.2f * e1;
        e2 = e2 > 0.f ? e2 : 0.2f * e2;
        e3 = e3 > 0.f ? e3 : 0.2f * e3;
        w4[j] = make_float4(__expf(e0), __expf(e1), __expf(e2), __expf(e3));
    }
}

// ---------------- precompute: wel/wer + W1^T + W2^T + zero counts/dhist/dfill ----------
__global__ void k_prep(const float* __restrict__ W1, const float* __restrict__ al,
                       const float* __restrict__ ar, const float* __restrict__ W2,
                       float* __restrict__ wel, float* __restrict__ wer,
                       unsigned short* __restrict__ W1Tb,
                       unsigned short* __restrict__ W2Tb,
                       int* __restrict__ counts, int* __restrict__ dhist,
                       int* __restrict__ dfill) {
    int gid = blockIdx.x * 256 + threadIdx.x;
    int nth = gridDim.x * 256;
    const int TOT = 512 + 32768 + 48 * 256;
    for (int i = gid; i < TOT; i += nth) {
        if (i < 512) {
            int k = i >> 2, h = i & 3;
            float a = 0.f, b = 0.f;
            for (int dd = 0; dd < 64; ++dd) {
                float w = W1[k * 256 + h * 64 + dd];
                a = fmaf(w, al[h * 64 + dd], a);
                b = fmaf(w, ar[h * 64 + dd], b);
            }
            wel[i] = a;            // i == k*4+h
            wer[i] = b;
        } else if (i < 512 + 32768) {
            int j = i - 512;
            int col = j >> 7, k = j & 127;
            W1Tb[j] = f2bf(W1[k * 256 + col]);      // W1T [256 cols][128 k] bf16
        } else {
            int j = i - 512 - 32768;
            int col = j >> 8, kk = j & 255;         // [48 cols][256 k]
            W2Tb[j] = (col < NCLS) ? f2bf(W2[kk * 40 + col]) : (unsigned short)0;
        }
    }
    for (int i = gid; i < NN; i += nth) counts[i] = 0;
    if (gid < 256) { dhist[gid] = 0; dfill[gid] = 0; }
}

// el1/er1[N,4] = x @ wel / x @ wer ; bf16 copy of x ; fused edge-count pass
__global__ void k_elr1x(const float* __restrict__ x, const float* __restrict__ wel,
                        const float* __restrict__ wer, float* __restrict__ el1,
                        float* __restrict__ er1, unsigned short* __restrict__ xb,
                        const int* __restrict__ dst, int* __restrict__ counts) {
    __shared__ float xs[64 * 129];
    __shared__ float wels[512], wers[512];
    int t = threadIdx.x;
    int n0 = blockIdx.x * 64;
    wels[t] = wel[t]; wels[256 + t] = wel[256 + t];
    wers[t] = wer[t]; wers[256 + t] = wer[256 + t];
    for (int i = 0; i < 8; ++i) {
        int f = i * 256 + t;
        int row = f >> 5;
        int col4 = (f & 31) * 4;
        float4 v = make_float4(0.f, 0.f, 0.f, 0.f);
        if (n0 + row < NN) v = ((const float4*)x)[(size_t)n0 * 32 + f];
        xs[row * 129 + col4 + 0] = v.x;
        xs[row * 129 + col4 + 1] = v.y;
        xs[row * 129 + col4 + 2] = v.z;
        xs[row * 129 + col4 + 3] = v.w;
    }
    __syncthreads();
    int node = t & 63;
    int h = t >> 6;
    float a = 0.f, b = 0.f;
    for (int k = 0; k < 128; ++k) {
        float xv = xs[node * 129 + k];
        a = fmaf(xv, wels[k * 4 + h], a);
        b = fmaf(xv, wers[k * 4 + h], b);
    }
    if (n0 + node < NN) {
        el1[(size_t)(n0 + node) * 4 + h] = a;
        er1[(size_t)(n0 + node) * 4 + h] = b;
    }
    for (int i = 0; i < 4; ++i) {
        int g = (i * 256 + t) * 8;
        int row = g >> 7, col = g & 127;
        if (n0 + row < NN) {
            ushort4 lo, hi;
            lo.x = f2bf(xs[row * 129 + col + 0]);
            lo.y = f2bf(xs[row * 129 + col + 1]);
            lo.z = f2bf(xs[row * 129 + col + 2]);
            lo.w = f2bf(xs[row * 129 + col + 3]);
            hi.x = f2bf(xs[row * 129 + col + 4]);
            hi.y = f2bf(xs[row * 129 + col + 5]);
            hi.z = f2bf(xs[row * 129 + col + 6]);
            hi.w = f2bf(xs[row * 129 + col + 7]);
            *(ushort4*)&xb[(size_t)(n0 + row) * 128 + col] = lo;
            *(ushort4*)&xb[(size_t)(n0 + row) * 128 + col + 4] = hi;
        }
    }
    // fused degree count (independent edge pass; overlaps with other blocks' compute)
    int gid = blockIdx.x * 256 + t;
    int nth = gridDim.x * 256;
    for (int e = gid; e < NE; e += nth) atomicAdd(&counts[dst[e]], 1);
}

// ---------------- fused layer-1+2a (degree-sorted dsts via perm) ----------------
// 256 thr / 4 waves / 16 dsts per block; gather(MLP16) -> MFMA@W1 -> ELU(LDS) -> MFMA@W2
#define XG_STRIDE 260      // uints per node (256 + 4 pad)
#define EB_STRIDE 264      // ushorts per node row (256 + 8 pad)
#define FMA8(AC0, AC1, AC2, AC3, WQ, XV) \
    AC0.x = fmaf(WQ.x, XV.x, AC0.x); AC0.y = fmaf(WQ.x, XV.y, AC0.y); \
    AC1.x = fmaf(WQ.y, XV.x, AC1.x); AC1.y = fmaf(WQ.y, XV.y, AC1.y); \
    AC2.x = fmaf(WQ.z, XV.x, AC2.x); AC2.y = fmaf(WQ.z, XV.y, AC2.y); \
    AC3.x = fmaf(WQ.w, XV.x, AC3.x); AC3.y = fmaf(WQ.w, XV.y, AC3.y);

__global__ void k_agg1m(const unsigned int* __restrict__ xb32,
                        const float4* __restrict__ w4,
                        const int* __restrict__ indptr, const int* __restrict__ srcs,
                        const int* __restrict__ perm,
                        const unsigned short* __restrict__ W1Tb,
                        const unsigned short* __restrict__ W2Tb,
                        const float* __restrict__ b1,
                        const float* __restrict__ al2, const float* __restrict__ ar2,
                        unsigned short* __restrict__ h2b,
                        float* __restrict__ el2, float* __restrict__ er2) {
    __shared__ unsigned int xg[16 * XG_STRIDE];            // 16.6 KB
    __shared__ __align__(16) unsigned char pool[10496];    // sw+si, later eb+pel/per
    __shared__ int pp[16];
    float4 (*sw)[64] = (float4(*)[64])pool;                // 8 KB
    int (*si)[64] = (int(*)[64])(pool + 8192);             // 2 KB
    unsigned short* eb = (unsigned short*)pool;            // [16][EB_STRIDE] = 8448 B
    float* pel = (float*)(pool + 8448);                    // [3][16]
    float* per_ = (float*)(pool + 8640);                   // [3][16]
    int t = threadIdx.x;
    int wv = t >> 6, l = t & 63;
    int n0 = blockIdx.x * 16;
    int d0 = n0 + wv * 4;
    if (t < 16) pp[t] = perm[n0 + t];
    int pm4[4], ipb[4], ipe[4];
#pragma unroll
    for (int q = 0; q < 4; ++q) pm4[q] = perm[d0 + q];
#pragma unroll
    for (int q = 0; q < 4; ++q) {
        ipb[q] = indptr[pm4[q]];
        ipe[q] = indptr[pm4[q] + 1];
    }
    int w2 = wv * 2;
#pragma unroll
    for (int p = 0; p < 2; ++p) {
        int begA = ipb[2 * p + 0], endA = ipe[2 * p + 0];
        int begB = ipb[2 * p + 1], endB = ipe[2 * p + 1];
        int degA = endA - begA, degB = endB - begB;
        // ---- coalesced weight+index load (raw weights from scatterw) ----
        int sA = 0, sB = 0;
        float4 wA = make_float4(0.f, 0.f, 0.f, 0.f);
        float4 wB = make_float4(0.f, 0.f, 0.f, 0.f);
        if (l < degA) { sA = srcs[begA + l]; wA = w4[begA + l]; }
        if (l < degB) { sB = srcs[begB + l]; wB = w4[begB + l]; }
        si[w2 + 0][l] = sA; sw[w2 + 0][l] = wA;
        si[w2 + 1][l] = sB; sw[w2 + 1][l] = wB;
        // ---- interleaved gather: up to 16 rows in flight ----
        float2 aA0 = {0,0}, aA1 = {0,0}, aA2 = {0,0}, aA3 = {0,0};
        float2 aB0 = {0,0}, aB1 = {0,0}, aB2 = {0,0}, aB3 = {0,0};
        int capA = degA < 64 ? degA : 64;
        int capB = degB < 64 ? degB : 64;
        int mcap = capA > capB ? capA : capB;
        for (int e = 0; e < mcap; e += 8) {
            unsigned int uA[8], uB[8];
            bool doA = e < capA, doB = e < capB;
            if (doA) {
#pragma unroll
                for (int q = 0; q < 8; ++q)
                    uA[q] = xb32[(size_t)si[w2][e + q] * 64 + l];
            }
            if (doB) {
#pragma unroll
                for (int q = 0; q < 8; ++q)
                    uB[q] = xb32[(size_t)si[w2 + 1][e + q] * 64 + l];
            }
            if (doA) {
#pragma unroll
                for (int q = 0; q < 8; ++q) {
                    float4 wq = sw[w2][e + q];
                    float2 xv = bf2x(uA[q]);
                    FMA8(aA0, aA1, aA2, aA3, wq, xv)
                }
            }
            if (doB) {
#pragma unroll
                for (int q = 0; q < 8; ++q) {
                    float4 wq = sw[w2 + 1][e + q];
                    float2 xv = bf2x(uB[q]);
                    FMA8(aB0, aB1, aB2, aB3, wq, xv)
                }
            }
        }
        // ---- deg>64 tails (rare) ----
        for (int j = begA + 64; j < endA; ++j) {
            float4 wq = w4[j];
            float2 xv = bf2x(xb32[(size_t)srcs[j] * 64 + l]);
            FMA8(aA0, aA1, aA2, aA3, wq, xv)
        }
        for (int j = begB + 64; j < endB; ++j) {
            float4 wq = w4[j];
            float2 xv = bf2x(xb32[(size_t)srcs[j] * 64 + l]);
            FMA8(aB0, aB1, aB2, aB3, wq, xv)
        }
        // ---- denominators (deferred) ----
        float dA0 = wA.x, dA1 = wA.y, dA2 = wA.z, dA3 = wA.w;
        float dB0 = wB.x, dB1 = wB.y, dB2 = wB.z, dB3 = wB.w;
        for (int j = begA + 64 + l; j < endA; j += 64) {
            float4 wt = w4[j];
            dA0 += wt.x; dA1 += wt.y; dA2 += wt.z; dA3 += wt.w;
        }
        for (int j = begB + 64 + l; j < endB; j += 64) {
            float4 wt = w4[j];
            dB0 += wt.x; dB1 += wt.y; dB2 += wt.z; dB3 += wt.w;
        }
#pragma unroll
        for (int off = 32; off > 0; off >>= 1) {
            dA0 += __shfl_xor(dA0, off); dA1 += __shfl_xor(dA1, off);
            dA2 += __shfl_xor(dA2, off); dA3 += __shfl_xor(dA3, off);
            dB0 += __shfl_xor(dB0, off); dB1 += __shfl_xor(dB1, off);
            dB2 += __shfl_xor(dB2, off); dB3 += __shfl_xor(dB3, off);
        }
        float iA0 = dA0 > 0.f ? 1.f / dA0 : 0.f;
        float iA1 = dA1 > 0.f ? 1.f / dA1 : 0.f;
        float iA2 = dA2 > 0.f ? 1.f / dA2 : 0.f;
        float iA3 = dA3 > 0.f ? 1.f / dA3 : 0.f;
        float iB0 = dB0 > 0.f ? 1.f / dB0 : 0.f;
        float iB1 = dB1 > 0.f ? 1.f / dB1 : 0.f;
        float iB2 = dB2 > 0.f ? 1.f / dB2 : 0.f;
        float iB3 = dB3 > 0.f ? 1.f / dB3 : 0.f;
        unsigned int* xgA = &xg[(wv * 4 + 2 * p + 0) * XG_STRIDE];
        xgA[0 * 64 + l] = pack2bf(aA0.x * iA0, aA0.y * iA0);
        xgA[1 * 64 + l] = pack2bf(aA1.x * iA1, aA1.y * iA1);
        xgA[2 * 64 + l] = pack2bf(aA2.x * iA2, aA2.y * iA2);
        xgA[3 * 64 + l] = pack2bf(aA3.x * iA3, aA3.y * iA3);
        unsigned int* xgB = &xg[(wv * 4 + 2 * p + 1) * XG_STRIDE];
        xgB[0 * 64 + l] = pack2bf(aB0.x * iB0, aB0.y * iB0);
        xgB[1 * 64 + l] = pack2bf(aB1.x * iB1, aB1.y * iB1);
        xgB[2 * 64 + l] = pack2bf(aB2.x * iB2, aB2.y * iB2);
        xgB[3 * 64 + l] = pack2bf(aB3.x * iB3, aB3.y * iB3);
    }
    __syncthreads();                 // xg + pp ready; pool (si/sw) dead
    // ---- MFMA1: wave wv = head wv; 16 nodes x 64 cols, K=128; ELU -> eb (LDS) ----
    int lrow = l & 15, lk = l >> 4;
    {
        f32x4 acc[4] = {};
#pragma unroll
        for (int kt = 0; kt < 4; ++kt) {
            bf16x8 av = *(const bf16x8*)&xg[lrow * XG_STRIDE + wv * 64 + kt * 16 + lk * 4];
#pragma unroll
            for (int nt = 0; nt < 4; ++nt) {
                int col = wv * 64 + nt * 16 + lrow;
                bf16x8 bv = *(const bf16x8*)&W1Tb[(size_t)col * 128 + kt * 32 + lk * 8];
                acc[nt] = __builtin_amdgcn_mfma_f32_16x16x32_bf16(av, bv, acc[nt], 0, 0, 0);
            }
        }
#pragma unroll
        for (int nt = 0; nt < 4; ++nt) {
            int col = wv * 64 + nt * 16 + lrow;
            float bv1 = b1[col];
#pragma unroll
            for (int r = 0; r < 4; ++r) {
                int rloc = lk * 4 + r;
                float o = acc[nt][r] + bv1;
                o = o > 0.f ? o : (__expf(o) - 1.f);
                eb[rloc * EB_STRIDE + col] = f2bf(o);
            }
        }
    }
    __syncthreads();                 // eb ready
    // ---- MFMA2: waves 0..2 compute col tiles 0..2 of [16,256]@[256,48] ----
    if (wv < 3) {
        f32x4 acc2 = {};
#pragma unroll
        for (int kt = 0; kt < 8; ++kt) {
            bf16x8 av = *(const bf16x8*)&eb[lrow * EB_STRIDE + kt * 32 + lk * 8];
            bf16x8 bv = *(const bf16x8*)&W2Tb[(size_t)(wv * 16 + lrow) * 256 + kt * 32 + lk * 8];
            acc2 = __builtin_amdgcn_mfma_f32_16x16x32_bf16(av, bv, acc2, 0, 0, 0);
        }
        int col2 = wv * 16 + lrow;
        float alc = col2 < NCLS ? al2[col2] : 0.f;
        float arc = col2 < NCLS ? ar2[col2] : 0.f;
#pragma unroll
        for (int r = 0; r < 4; ++r) {
            int rloc = lk * 4 + r;
            int row = pp[rloc];
            float v = acc2[r];
            if (col2 < NCLS) h2b[(size_t)row * NCLS + col2] = f2bf(v);
            float pa = v * alc, pb = v * arc;
#pragma unroll
            for (int off = 1; off < 16; off <<= 1) {
                pa += __shfl_xor(pa, off);
                pb += __shfl_xor(pb, off);
            }
            if (lrow == 0) {
                pel[wv * 16 + rloc] = pa;
                per_[wv * 16 + rloc] = pb;
            }
        }
    }
    __syncthreads();
    if (t < 16) {
        int row = pp[t];
        el2[row] = pel[t] + pel[16 + t] + pel[32 + t];
        er2[row] = per_[t] + per_[16 + t] + per_[32 + t];
    }
}

// merged layer-2 softmax + aggregation: 2 (degree-matched) dsts per wave, MLP16
__global__ void k_agg2(const unsigned int* __restrict__ h2b32,
                       const float* __restrict__ el2,
                       const float* __restrict__ er2, const float* __restrict__ b2,
                       const int* __restrict__ indptr, const int* __restrict__ srcs,
                       const int* __restrict__ perm,
                       float* __restrict__ out) {
    __shared__ int   si[8][64];
    __shared__ float sw[8][64];
    int t = threadIdx.x;
    int wv = t >> 6, l = t & 63;
    int base8 = blockIdx.x * 8;
    int dA = perm[base8 + wv * 2];
    int dB = perm[base8 + wv * 2 + 1];
    int begA = indptr[dA], endA = indptr[dA + 1];
    int begB = indptr[dB], endB = indptr[dB + 1];
    int degA = endA - begA, degB = endB - begB;
    float rdA = er2[dA], rdB = er2[dB];
    int sA = 0, sB = 0;
    float wA = 0.f, wB = 0.f;
    if (l < degA) {
        sA = srcs[begA + l];
        float e = el2[sA] + rdA;
        e = e > 0.f ? e : 0.2f * e;
        wA = __expf(e);
    }
    if (l < degB) {
        sB = srcs[begB + l];
        float e = el2[sB] + rdB;
        e = e > 0.f ? e : 0.2f * e;
        wB = __expf(e);
    }
    int w2 = wv * 2;
    si[w2 + 0][l] = sA; sw[w2 + 0][l] = wA;
    si[w2 + 1][l] = sB; sw[w2 + 1][l] = wB;
    float denA = wA, denB = wB;
    for (int j = begA + 64 + l; j < endA; j += 64) {
        float e = el2[srcs[j]] + rdA;
        e = e > 0.f ? e : 0.2f * e;
        denA += __expf(e);
    }
    for (int j = begB + 64 + l; j < endB; j += 64) {
        float e = el2[srcs[j]] + rdB;
        e = e > 0.f ? e : 0.2f * e;
        denB += __expf(e);
    }
    // payload: half-wave edge split; lane il holds cols {2*il, 2*il+1}
    int half = l >> 5, il = l & 31;
    bool act = il < 20;
    float2 accA = {0.f, 0.f}, accB = {0.f, 0.f};
    int capA = degA < 64 ? degA : 64;
    int capB = degB < 64 ? degB : 64;
    int mcap = capA > capB ? capA : capB;
    for (int e = 0; e < mcap; e += 8) {
        bool doA = e < capA, doB = e < capB;
        int ixA[4], ixB[4];
        float wsA[4], wsB[4];
        unsigned int uA[4], uB[4];
        if (doA) {
#pragma unroll
            for (int q = 0; q < 4; ++q) {
                int idx = e + 2 * q + half;
                ixA[q] = si[w2][idx];
                wsA[q] = sw[w2][idx];
            }
        }
        if (doB) {
#pragma unroll
            for (int q = 0; q < 4; ++q) {
                int idx = e + 2 * q + half;
                ixB[q] = si[w2 + 1][idx];
                wsB[q] = sw[w2 + 1][idx];
            }
        }
        if (doA) {
#pragma unroll
            for (int q = 0; q < 4; ++q)
                uA[q] = act ? h2b32[(size_t)ixA[q] * 20 + il] : 0u;
        }
        if (doB) {
#pragma unroll
            for (int q = 0; q < 4; ++q)
                uB[q] = act ? h2b32[(size_t)ixB[q] * 20 + il] : 0u;
        }
        if (doA) {
#pragma unroll
            for (int q = 0; q < 4; ++q) {
                float2 xv = bf2x(uA[q]);
                accA.x = fmaf(wsA[q], xv.x, accA.x);
                accA.y = fmaf(wsA[q], xv.y, accA.y);
            }
        }
        if (doB) {
#pragma unroll
            for (int q = 0; q < 4; ++q) {
                float2 xv = bf2x(uB[q]);
                accB.x = fmaf(wsB[q], xv.x, accB.x);
                accB.y = fmaf(wsB[q], xv.y, accB.y);
            }
        }
    }
    for (int j = begA + 64; j < endA; ++j) {     // deg>64 (rare)
        int s = srcs[j];
        float e = el2[s] + rdA;
        e = e > 0.f ? e : 0.2f * e;
        float ww = (half == 0) ? __expf(e) : 0.f;
        unsigned int u = act ? h2b32[(size_t)s * 20 + il] : 0u;
        float2 xv = bf2x(u);
        accA.x = fmaf(ww, xv.x, accA.x);
        accA.y = fmaf(ww, xv.y, accA.y);
    }
    for (int j = begB + 64; j < endB; ++j) {
        int s = srcs[j];
        float e = el2[s] + rdB;
        e = e > 0.f ? e : 0.2f * e;
        float ww = (half == 0) ? __expf(e) : 0.f;
        unsigned int u = act ? h2b32[(size_t)s * 20 + il] : 0u;
        float2 xv = bf2x(u);
        accB.x = fmaf(ww, xv.x, accB.x);
        accB.y = fmaf(ww, xv.y, accB.y);
    }
    // deferred: reduce dens over the full wave, after the loads
#pragma unroll
    for (int off = 32; off > 0; off >>= 1) {
        denA += __shfl_xor(denA, off);
        denB += __shfl_xor(denB, off);
    }
    float invA = denA > 0.f ? 1.f / denA : 0.f;
    float invB = denB > 0.f ? 1.f / denB : 0.f;
    accA.x += __shfl_xor(accA.x, 32);
    accA.y += __shfl_xor(accA.y, 32);
    accB.x += __shfl_xor(accB.x, 32);
    accB.y += __shfl_xor(accB.y, 32);
    if (half == 0 && act) {
        float2 bb = *(const float2*)&b2[2 * il];
        *(float2*)&out[(size_t)dA * NCLS + 2 * il] =
            make_float2(fmaf(accA.x, invA, bb.x), fmaf(accA.y, invA, bb.y));
        *(float2*)&out[(size_t)dB * NCLS + 2 * il] =
            make_float2(fmaf(accB.x, invB, bb.x), fmaf(accB.y, invB, bb.y));
    }
}

extern "C" void kernel_launch(void* const* d_in, const int* in_sizes, int n_in,
                              void* d_out, int out_size, void* d_ws, size_t ws_size,
                              hipStream_t stream) {
    const float* x   = (const float*)d_in[0];
    const int*   src = (const int*)d_in[1];
    const int*   dst = (const int*)d_in[2];
    const float* W1  = (const float*)d_in[3];
    const float* al1 = (const float*)d_in[4];
    const float* ar1 = (const float*)d_in[5];
    const float* b1  = (const float*)d_in[6];
    const float* W2  = (const float*)d_in[7];
    const float* al2 = (const float*)d_in[8];
    const float* ar2 = (const float*)d_in[9];
    const float* b2  = (const float*)d_in[10];
    float* out = (float*)d_out;

    float* ws = (float*)d_ws;
    size_t off = 0;
    unsigned short* xb    = (unsigned short*)(ws + off); off += (size_t)NN * 64;  // bf16 [N,128]
    unsigned short* h2b   = (unsigned short*)(ws + off); off += (size_t)NN * 20;  // bf16 [N,40]
    float* el1  = ws + off; off += (size_t)NN * 4;
    float* er1  = ws + off; off += (size_t)NN * 4;
    float* el2  = ws + off; off += NN;
    float* er2  = ws + off; off += NN;
    float* wel  = ws + off; off += 512;
    float* wer  = ws + off; off += 512;
    unsigned short* w1tb = (unsigned short*)(ws + off); off += 16384;             // bf16 [256,128]
    unsigned short* w2tb = (unsigned short*)(ws + off); off += 48 * 128;          // bf16 [48,256]
    float* w4   = ws + off; off += (size_t)NE * 4;                                // raw weights, CSR order
    int* counts = (int*)(ws + off);
    int* indptr = counts + NN;
    int* fill   = indptr + NN + 1;
    int* srcs   = fill + NN;
    int* bsum   = srcs + NE;
    int* dhist  = bsum + 256;
    int* dfill  = dhist + 256;
    int* perm   = dfill + 256;

    const int NB = (NN + 255) / 256;

    k_prep<<<48, 256, 0, stream>>>(W1, al1, ar1, W2, wel, wer, w1tb, w2tb,
                                   counts, dhist, dfill);
    k_elr1x<<<(NN + 63) / 64, 256, 0, stream>>>(x, wel, wer, el1, er1, xb, dst, counts);
    k_scanA<<<NB, 256, 0, stream>>>(counts, indptr, bsum, dhist);
    k_scanB<<<1, 256, 0, stream>>>(bsum, NB, dhist);
    k_scanC<<<NB, 256, 0, stream>>>(indptr, bsum, fill, counts, dhist, dfill, perm);
    k_scatterw<<<(NE + 255) / 256, 256, 0, stream>>>(src, dst, indptr, fill,
                                                     el1, er1, srcs, (float4*)w4);
    k_agg1m<<<NN / 16, 256, 0, stream>>>((const unsigned int*)xb, (const float4*)w4,
                                         indptr, srcs, perm, w1tb, w2tb, b1, al2, ar2,
                                         h2b, el2, er2);

    k_agg2<<<NN / 8, 256, 0, stream>>>((const unsigned int*)h2b, el2, er2, b2,
                                       indptr, srcs, perm, out);
}

// Round 20
// 214.799 us; speedup vs baseline: 2.0818x; 2.0818x over previous
//
#include <hip/hip_runtime.h>

#define NN 50000
#define NE 800000
#define HID 256
#define NCLS 40
#define NB_SCAN 196     // ceil(NN/256)

typedef short bf16x8 __attribute__((ext_vector_type(8)));
typedef float f32x4 __attribute__((ext_vector_type(4)));

__device__ inline unsigned short f2bf(float f) {            // RNE float->bf16
    unsigned int u = __float_as_uint(f);
    return (unsigned short)((u + 0x7FFFu + ((u >> 16) & 1u)) >> 16);
}
__device__ inline unsigned int pack2bf(float a, float b) {
    return (unsigned int)f2bf(a) | ((unsigned int)f2bf(b) << 16);
}
__device__ inline float2 bf2x(unsigned int u) {             // 2 bf16 -> 2 f32
    return make_float2(__uint_as_float(u << 16), __uint_as_float(u & 0xFFFF0000u));
}

// ---------------- CSR build + privatized degree histogram ----------------
__global__ void k_scanA(const int* __restrict__ counts, int* __restrict__ indptr,
                        int* __restrict__ bsum, int* __restrict__ dblk) {
    __shared__ int sh[256];
    __shared__ int lh[256];
    int t = threadIdx.x;
    int idx = blockIdx.x * 256 + t;
    int c = idx < NN ? counts[idx] : 0;
    lh[t] = 0;
    sh[t] = c;
    __syncthreads();
    for (int off = 1; off < 256; off <<= 1) {
        int v = (t >= off) ? sh[t - off] : 0;
        __syncthreads();
        sh[t] += v;
        __syncthreads();
    }
    if (idx < NN) {
        indptr[idx] = sh[t] - c;
        int b = c < 255 ? c : 255;
        atomicAdd(&lh[b], 1);                 // LDS atomic, block-local
    }
    if (t == 255) bsum[blockIdx.x] = sh[255];
    __syncthreads();
    dblk[blockIdx.x * 256 + t] = lh[t];       // per-block histogram
}

// scan block sums; column-prefix the block histograms; scan bin totals
__global__ void k_scanB(int* __restrict__ bsum, int nb, int* __restrict__ dblk,
                        int* __restrict__ dhist) {
    __shared__ int sh[256];
    int t = threadIdx.x;
    int c = t < nb ? bsum[t] : 0;
    sh[t] = c;
    __syncthreads();
    for (int off = 1; off < 256; off <<= 1) {
        int v = (t >= off) ? sh[t - off] : 0;
        __syncthreads();
        sh[t] += v;
        __syncthreads();
    }
    if (t < nb) bsum[t] = sh[t] - c;
    __syncthreads();
    // column prefix over blocks for bin t (dblk[blk][t] -> base of blk within bin t)
    int run = 0;
    for (int blk = 0; blk < NB_SCAN; ++blk) {
        int v = dblk[blk * 256 + t];
        dblk[blk * 256 + t] = run;
        run += v;
    }
    sh[t] = run;                              // total nodes in bin t
    __syncthreads();
    for (int off = 1; off < 256; off <<= 1) {
        int v = (t >= off) ? sh[t - off] : 0;
        __syncthreads();
        sh[t] += v;
        __syncthreads();
    }
    dhist[t] = sh[t] - run;                   // exclusive base per bin
}

// finalize indptr, zero fill, scatter degree-sorted permutation (LDS positions)
__global__ void k_scanC(int* __restrict__ indptr, const int* __restrict__ bsum,
                        int* __restrict__ fill, const int* __restrict__ counts,
                        const int* __restrict__ dhist, const int* __restrict__ dblk,
                        int* __restrict__ perm) {
    __shared__ int lh[256];
    int t = threadIdx.x;
    int idx = blockIdx.x * 256 + t;
    lh[t] = 0;
    __syncthreads();
    if (idx < NN) {
        indptr[idx] += bsum[idx >> 8];
        fill[idx] = 0;
        int c = counts[idx];
        int b = c < 255 ? c : 255;
        int pos = atomicAdd(&lh[b], 1);       // intra-block position (LDS)
        perm[dhist[b] + dblk[blockIdx.x * 256 + b] + pos] = idx;
    }
    if (idx == 0) indptr[NN] = NE;
}

// scatter + fused layer-1 edge weights (raw, unnormalized) in CSR order
__global__ void k_scatterw(const int* __restrict__ src, const int* __restrict__ dst,
                           const int* __restrict__ indptr, int* __restrict__ fill,
                           const float* __restrict__ el1, const float* __restrict__ er1,
                           int* __restrict__ srcs, float4* __restrict__ w4) {
    int e = blockIdx.x * 256 + threadIdx.x;
    if (e < NE) {
        int d = dst[e];
        int s = src[e];
        int pos = atomicAdd(&fill[d], 1);
        int j = indptr[d] + pos;
        srcs[j] = s;
        float4 ls = *(const float4*)&el1[(size_t)s * 4];
        float4 rd = *(const float4*)&er1[(size_t)d * 4];
        float e0 = ls.x + rd.x, e1 = ls.y + rd.y, e2 = ls.z + rd.z, e3 = ls.w + rd.w;
        e0 = e0 > 0.f ? e0 : 0.2f * e0;
        e1 = e1 > 0.f ? e1 : 0.2f * e1;
        e2 = e2 > 0.f ? e2 : 0.2f * e2;
        e3 = e3 > 0.f ? e3 : 0.2f * e3;
        w4[j] = make_float4(__expf(e0), __expf(e1), __expf(e2), __expf(e3));
    }
}

// ---------------- precompute: wel/wer + W1^T(bf16) + W2^T(bf16) + zero counts ----------
__global__ void k_prep(const float* __restrict__ W1, const float* __restrict__ al,
                       const float* __restrict__ ar, const float* __restrict__ W2,
                       float* __restrict__ wel, float* __restrict__ wer,
                       unsigned short* __restrict__ W1Tb,
                       unsigned short* __restrict__ W2Tb,
                       int* __restrict__ counts) {
    int gid = blockIdx.x * 256 + threadIdx.x;
    int nth = gridDim.x * 256;
    const int TOT = 512 + 32768 + 48 * 256;
    for (int i = gid; i < TOT; i += nth) {
        if (i < 512) {
            int k = i >> 2, h = i & 3;
            float a = 0.f, b = 0.f;
            for (int dd = 0; dd < 64; ++dd) {
                float w = W1[k * 256 + h * 64 + dd];
                a = fmaf(w, al[h * 64 + dd], a);
                b = fmaf(w, ar[h * 64 + dd], b);
            }
            wel[i] = a;            // i == k*4+h
            wer[i] = b;
        } else if (i < 512 + 32768) {
            int j = i - 512;
            int col = j >> 7, k = j & 127;
            W1Tb[j] = f2bf(W1[k * 256 + col]);      // W1T [256 cols][128 k] bf16
        } else {
            int j = i - 512 - 32768;
            int col = j >> 8, kk = j & 255;         // [48 cols][256 k]
            W2Tb[j] = (col < NCLS) ? f2bf(W2[kk * 40 + col]) : (unsigned short)0;
        }
    }
    for (int i = gid; i < NN; i += nth) counts[i] = 0;
}

// el1/er1[N,4] = x @ wel / x @ wer ; bf16 copy of x ; fused edge-count pass
__global__ void k_elr1x(const float* __restrict__ x, const float* __restrict__ wel,
                        const float* __restrict__ wer, float* __restrict__ el1,
                        float* __restrict__ er1, unsigned short* __restrict__ xb,
                        const int* __restrict__ dst, int* __restrict__ counts) {
    __shared__ float xs[64 * 129];
    __shared__ float wels[512], wers[512];
    int t = threadIdx.x;
    int n0 = blockIdx.x * 64;
    wels[t] = wel[t]; wels[256 + t] = wel[256 + t];
    wers[t] = wer[t]; wers[256 + t] = wer[256 + t];
    for (int i = 0; i < 8; ++i) {
        int f = i * 256 + t;
        int row = f >> 5;
        int col4 = (f & 31) * 4;
        float4 v = make_float4(0.f, 0.f, 0.f, 0.f);
        if (n0 + row < NN) v = ((const float4*)x)[(size_t)n0 * 32 + f];
        xs[row * 129 + col4 + 0] = v.x;
        xs[row * 129 + col4 + 1] = v.y;
        xs[row * 129 + col4 + 2] = v.z;
        xs[row * 129 + col4 + 3] = v.w;
    }
    __syncthreads();
    int node = t & 63;
    int h = t >> 6;
    float a = 0.f, b = 0.f;
    for (int k = 0; k < 128; ++k) {
        float xv = xs[node * 129 + k];
        a = fmaf(xv, wels[k * 4 + h], a);
        b = fmaf(xv, wers[k * 4 + h], b);
    }
    if (n0 + node < NN) {
        el1[(size_t)(n0 + node) * 4 + h] = a;
        er1[(size_t)(n0 + node) * 4 + h] = b;
    }
    for (int i = 0; i < 4; ++i) {
        int g = (i * 256 + t) * 8;
        int row = g >> 7, col = g & 127;
        if (n0 + row < NN) {
            ushort4 lo, hi;
            lo.x = f2bf(xs[row * 129 + col + 0]);
            lo.y = f2bf(xs[row * 129 + col + 1]);
            lo.z = f2bf(xs[row * 129 + col + 2]);
            lo.w = f2bf(xs[row * 129 + col + 3]);
            hi.x = f2bf(xs[row * 129 + col + 4]);
            hi.y = f2bf(xs[row * 129 + col + 5]);
            hi.z = f2bf(xs[row * 129 + col + 6]);
            hi.w = f2bf(xs[row * 129 + col + 7]);
            *(ushort4*)&xb[(size_t)(n0 + row) * 128 + col] = lo;
            *(ushort4*)&xb[(size_t)(n0 + row) * 128 + col + 4] = hi;
        }
    }
    // fused degree count (independent edge pass; overlaps with other blocks' compute)
    int gid = blockIdx.x * 256 + t;
    int nth = gridDim.x * 256;
    for (int e = gid; e < NE; e += nth) atomicAdd(&counts[dst[e]], 1);
}

// ---------------- fused layer-1+2a (degree-sorted dsts via perm) ----------------
// 256 thr / 4 waves / 16 dsts per block; gather(MLP16) -> MFMA@W1 -> ELU(LDS) -> MFMA@W2
#define XG_STRIDE 260      // uints per node (256 + 4 pad)
#define EB_STRIDE 264      // ushorts per node row (256 + 8 pad)
#define FMA8(AC0, AC1, AC2, AC3, WQ, XV) \
    AC0.x = fmaf(WQ.x, XV.x, AC0.x); AC0.y = fmaf(WQ.x, XV.y, AC0.y); \
    AC1.x = fmaf(WQ.y, XV.x, AC1.x); AC1.y = fmaf(WQ.y, XV.y, AC1.y); \
    AC2.x = fmaf(WQ.z, XV.x, AC2.x); AC2.y = fmaf(WQ.z, XV.y, AC2.y); \
    AC3.x = fmaf(WQ.w, XV.x, AC3.x); AC3.y = fmaf(WQ.w, XV.y, AC3.y);

__global__ void k_agg1m(const unsigned int* __restrict__ xb32,
                        const float4* __restrict__ w4,
                        const int* __restrict__ indptr, const int* __restrict__ srcs,
                        const int* __restrict__ perm,
                        const unsigned short* __restrict__ W1Tb,
                        const unsigned short* __restrict__ W2Tb,
                        const float* __restrict__ b1,
                        const float* __restrict__ al2, const float* __restrict__ ar2,
                        unsigned short* __restrict__ h2b,
                        float* __restrict__ el2, float* __restrict__ er2) {
    __shared__ unsigned int xg[16 * XG_STRIDE];            // 16.6 KB
    __shared__ __align__(16) unsigned char pool[10496];    // sw+si, later eb+pel/per
    __shared__ int pp[16];
    float4 (*sw)[64] = (float4(*)[64])pool;                // 8 KB
    int (*si)[64] = (int(*)[64])(pool + 8192);             // 2 KB
    unsigned short* eb = (unsigned short*)pool;            // [16][EB_STRIDE] = 8448 B
    float* pel = (float*)(pool + 8448);                    // [3][16]
    float* per_ = (float*)(pool + 8640);                   // [3][16]
    int t = threadIdx.x;
    int wv = t >> 6, l = t & 63;
    int n0 = blockIdx.x * 16;
    int d0 = n0 + wv * 4;
    if (t < 16) pp[t] = perm[n0 + t];
    int pm4[4], ipb[4], ipe[4];
#pragma unroll
    for (int q = 0; q < 4; ++q) pm4[q] = perm[d0 + q];
#pragma unroll
    for (int q = 0; q < 4; ++q) {
        ipb[q] = indptr[pm4[q]];
        ipe[q] = indptr[pm4[q] + 1];
    }
    int w2 = wv * 2;
#pragma unroll
    for (int p = 0; p < 2; ++p) {
        int begA = ipb[2 * p + 0], endA = ipe[2 * p + 0];
        int begB = ipb[2 * p + 1], endB = ipe[2 * p + 1];
        int degA = endA - begA, degB = endB - begB;
        // ---- coalesced weight+index load (raw weights from scatterw) ----
        int sA = 0, sB = 0;
        float4 wA = make_float4(0.f, 0.f, 0.f, 0.f);
        float4 wB = make_float4(0.f, 0.f, 0.f, 0.f);
        if (l < degA) { sA = srcs[begA + l]; wA = w4[begA + l]; }
        if (l < degB) { sB = srcs[begB + l]; wB = w4[begB + l]; }
        si[w2 + 0][l] = sA; sw[w2 + 0][l] = wA;
        si[w2 + 1][l] = sB; sw[w2 + 1][l] = wB;
        // ---- interleaved gather: up to 16 rows in flight ----
        float2 aA0 = {0,0}, aA1 = {0,0}, aA2 = {0,0}, aA3 = {0,0};
        float2 aB0 = {0,0}, aB1 = {0,0}, aB2 = {0,0}, aB3 = {0,0};
        int capA = degA < 64 ? degA : 64;
        int capB = degB < 64 ? degB : 64;
        int mcap = capA > capB ? capA : capB;
        for (int e = 0; e < mcap; e += 8) {
            unsigned int uA[8], uB[8];
            bool doA = e < capA, doB = e < capB;
            if (doA) {
#pragma unroll
                for (int q = 0; q < 8; ++q)
                    uA[q] = xb32[(size_t)si[w2][e + q] * 64 + l];
            }
            if (doB) {
#pragma unroll
                for (int q = 0; q < 8; ++q)
                    uB[q] = xb32[(size_t)si[w2 + 1][e + q] * 64 + l];
            }
            if (doA) {
#pragma unroll
                for (int q = 0; q < 8; ++q) {
                    float4 wq = sw[w2][e + q];
                    float2 xv = bf2x(uA[q]);
                    FMA8(aA0, aA1, aA2, aA3, wq, xv)
                }
            }
            if (doB) {
#pragma unroll
                for (int q = 0; q < 8; ++q) {
                    float4 wq = sw[w2 + 1][e + q];
                    float2 xv = bf2x(uB[q]);
                    FMA8(aB0, aB1, aB2, aB3, wq, xv)
                }
            }
        }
        // ---- deg>64 tails (rare) ----
        for (int j = begA + 64; j < endA; ++j) {
            float4 wq = w4[j];
            float2 xv = bf2x(xb32[(size_t)srcs[j] * 64 + l]);
            FMA8(aA0, aA1, aA2, aA3, wq, xv)
        }
        for (int j = begB + 64; j < endB; ++j) {
            float4 wq = w4[j];
            float2 xv = bf2x(xb32[(size_t)srcs[j] * 64 + l]);
            FMA8(aB0, aB1, aB2, aB3, wq, xv)
        }
        // ---- denominators (deferred) ----
        float dA0 = wA.x, dA1 = wA.y, dA2 = wA.z, dA3 = wA.w;
        float dB0 = wB.x, dB1 = wB.y, dB2 = wB.z, dB3 = wB.w;
        for (int j = begA + 64 + l; j < endA; j += 64) {
            float4 wt = w4[j];
            dA0 += wt.x; dA1 += wt.y; dA2 += wt.z; dA3 += wt.w;
        }
        for (int j = begB + 64 + l; j < endB; j += 64) {
            float4 wt = w4[j];
            dB0 += wt.x; dB1 += wt.y; dB2 += wt.z; dB3 += wt.w;
        }
#pragma unroll
        for (int off = 32; off > 0; off >>= 1) {
            dA0 += __shfl_xor(dA0, off); dA1 += __shfl_xor(dA1, off);
            dA2 += __shfl_xor(dA2, off); dA3 += __shfl_xor(dA3, off);
            dB0 += __shfl_xor(dB0, off); dB1 += __shfl_xor(dB1, off);
            dB2 += __shfl_xor(dB2, off); dB3 += __shfl_xor(dB3, off);
        }
        float iA0 = dA0 > 0.f ? 1.f / dA0 : 0.f;
        float iA1 = dA1 > 0.f ? 1.f / dA1 : 0.f;
        float iA2 = dA2 > 0.f ? 1.f / dA2 : 0.f;
        float iA3 = dA3 > 0.f ? 1.f / dA3 : 0.f;
        float iB0 = dB0 > 0.f ? 1.f / dB0 : 0.f;
        float iB1 = dB1 > 0.f ? 1.f / dB1 : 0.f;
        float iB2 = dB2 > 0.f ? 1.f / dB2 : 0.f;
        float iB3 = dB3 > 0.f ? 1.f / dB3 : 0.f;
        unsigned int* xgA = &xg[(wv * 4 + 2 * p + 0) * XG_STRIDE];
        xgA[0 * 64 + l] = pack2bf(aA0.x * iA0, aA0.y * iA0);
        xgA[1 * 64 + l] = pack2bf(aA1.x * iA1, aA1.y * iA1);
        xgA[2 * 64 + l] = pack2bf(aA2.x * iA2, aA2.y * iA2);
        xgA[3 * 64 + l] = pack2bf(aA3.x * iA3, aA3.y * iA3);
        unsigned int* xgB = &xg[(wv * 4 + 2 * p + 1) * XG_STRIDE];
        xgB[0 * 64 + l] = pack2bf(aB0.x * iB0, aB0.y * iB0);
        xgB[1 * 64 + l] = pack2bf(aB1.x * iB1, aB1.y * iB1);
        xgB[2 * 64 + l] = pack2bf(aB2.x * iB2, aB2.y * iB2);
        xgB[3 * 64 + l] = pack2bf(aB3.x * iB3, aB3.y * iB3);
    }
    __syncthreads();                 // xg + pp ready; pool (si/sw) dead
    // ---- MFMA1: wave wv = head wv; 16 nodes x 64 cols, K=128; ELU -> eb (LDS) ----
    int lrow = l & 15, lk = l >> 4;
    {
        f32x4 acc[4] = {};
#pragma unroll
        for (int kt = 0; kt < 4; ++kt) {
            bf16x8 av = *(const bf16x8*)&xg[lrow * XG_STRIDE + wv * 64 + kt * 16 + lk * 4];
#pragma unroll
            for (int nt = 0; nt < 4; ++nt) {
                int col = wv * 64 + nt * 16 + lrow;
                bf16x8 bv = *(const bf16x8*)&W1Tb[(size_t)col * 128 + kt * 32 + lk * 8];
                acc[nt] = __builtin_amdgcn_mfma_f32_16x16x32_bf16(av, bv, acc[nt], 0, 0, 0);
            }
        }
#pragma unroll
        for (int nt = 0; nt < 4; ++nt) {
            int col = wv * 64 + nt * 16 + lrow;
            float bv1 = b1[col];
#pragma unroll
            for (int r = 0; r < 4; ++r) {
                int rloc = lk * 4 + r;
                float o = acc[nt][r] + bv1;
                o = o > 0.f ? o : (__expf(o) - 1.f);
                eb[rloc * EB_STRIDE + col] = f2bf(o);
            }
        }
    }
    __syncthreads();                 // eb ready
    // ---- MFMA2: waves 0..2 compute col tiles 0..2 of [16,256]@[256,48] ----
    if (wv < 3) {
        f32x4 acc2 = {};
#pragma unroll
        for (int kt = 0; kt < 8; ++kt) {
            bf16x8 av = *(const bf16x8*)&eb[lrow * EB_STRIDE + kt * 32 + lk * 8];
            bf16x8 bv = *(const bf16x8*)&W2Tb[(size_t)(wv * 16 + lrow) * 256 + kt * 32 + lk * 8];
            acc2 = __builtin_amdgcn_mfma_f32_16x16x32_bf16(av, bv, acc2, 0, 0, 0);
        }
        int col2 = wv * 16 + lrow;
        float alc = col2 < NCLS ? al2[col2] : 0.f;
        float arc = col2 < NCLS ? ar2[col2] : 0.f;
#pragma unroll
        for (int r = 0; r < 4; ++r) {
            int rloc = lk * 4 + r;
            int row = pp[rloc];
            float v = acc2[r];
            if (col2 < NCLS) h2b[(size_t)row * NCLS + col2] = f2bf(v);
            float pa = v * alc, pb = v * arc;
#pragma unroll
            for (int off = 1; off < 16; off <<= 1) {
                pa += __shfl_xor(pa, off);
                pb += __shfl_xor(pb, off);
            }
            if (lrow == 0) {
                pel[wv * 16 + rloc] = pa;
                per_[wv * 16 + rloc] = pb;
            }
        }
    }
    __syncthreads();
    if (t < 16) {
        int row = pp[t];
        el2[row] = pel[t] + pel[16 + t] + pel[32 + t];
        er2[row] = per_[t] + per_[16 + t] + per_[32 + t];
    }
}

// merged layer-2 softmax + aggregation: 2 (degree-matched) dsts per wave, MLP16
__global__ void k_agg2(const unsigned int* __restrict__ h2b32,
                       const float* __restrict__ el2,
                       const float* __restrict__ er2, const float* __restrict__ b2,
                       const int* __restrict__ indptr, const int* __restrict__ srcs,
                       const int* __restrict__ perm,
                       float* __restrict__ out) {
    __shared__ int   si[8][64];
    __shared__ float sw[8][64];
    int t = threadIdx.x;
    int wv = t >> 6, l = t & 63;
    int base8 = blockIdx.x * 8;
    int dA = perm[base8 + wv * 2];
    int dB = perm[base8 + wv * 2 + 1];
    int begA = indptr[dA], endA = indptr[dA + 1];
    int begB = indptr[dB], endB = indptr[dB + 1];
    int degA = endA - begA, degB = endB - begB;
    float rdA = er2[dA], rdB = er2[dB];
    int sA = 0, sB = 0;
    float wA = 0.f, wB = 0.f;
    if (l < degA) {
        sA = srcs[begA + l];
        float e = el2[sA] + rdA;
        e = e > 0.f ? e : 0.2f * e;
        wA = __expf(e);
    }
    if (l < degB) {
        sB = srcs[begB + l];
        float e = el2[sB] + rdB;
        e = e > 0.f ? e : 0.2f * e;
        wB = __expf(e);
    }
    int w2 = wv * 2;
    si[w2 + 0][l] = sA; sw[w2 + 0][l] = wA;
    si[w2 + 1][l] = sB; sw[w2 + 1][l] = wB;
    float denA = wA, denB = wB;
    for (int j = begA + 64 + l; j < endA; j += 64) {
        float e = el2[srcs[j]] + rdA;
        e = e > 0.f ? e : 0.2f * e;
        denA += __expf(e);
    }
    for (int j = begB + 64 + l; j < endB; j += 64) {
        float e = el2[srcs[j]] + rdB;
        e = e > 0.f ? e : 0.2f * e;
        denB += __expf(e);
    }
    // payload: half-wave edge split; lane il holds cols {2*il, 2*il+1}
    int half = l >> 5, il = l & 31;
    bool act = il < 20;
    float2 accA = {0.f, 0.f}, accB = {0.f, 0.f};
    int capA = degA < 64 ? degA : 64;
    int capB = degB < 64 ? degB : 64;
    int mcap = capA > capB ? capA : capB;
    for (int e = 0; e < mcap; e += 8) {
        bool doA = e < capA, doB = e < capB;
        int ixA[4], ixB[4];
        float wsA[4], wsB[4];
        unsigned int uA[4], uB[4];
        if (doA) {
#pragma unroll
            for (int q = 0; q < 4; ++q) {
                int idx = e + 2 * q + half;
                ixA[q] = si[w2][idx];
                wsA[q] = sw[w2][idx];
            }
        }
        if (doB) {
#pragma unroll
            for (int q = 0; q < 4; ++q) {
                int idx = e + 2 * q + half;
                ixB[q] = si[w2 + 1][idx];
                wsB[q] = sw[w2 + 1][idx];
            }
        }
        if (doA) {
#pragma unroll
            for (int q = 0; q < 4; ++q)
                uA[q] = act ? h2b32[(size_t)ixA[q] * 20 + il] : 0u;
        }
        if (doB) {
#pragma unroll
            for (int q = 0; q < 4; ++q)
                uB[q] = act ? h2b32[(size_t)ixB[q] * 20 + il] : 0u;
        }
        if (doA) {
#pragma unroll
            for (int q = 0; q < 4; ++q) {
                float2 xv = bf2x(uA[q]);
                accA.x = fmaf(wsA[q], xv.x, accA.x);
                accA.y = fmaf(wsA[q], xv.y, accA.y);
            }
        }
        if (doB) {
#pragma unroll
            for (int q = 0; q < 4; ++q) {
                float2 xv = bf2x(uB[q]);
                accB.x = fmaf(wsB[q], xv.x, accB.x);
                accB.y = fmaf(wsB[q], xv.y, accB.y);
            }
        }
    }
    for (int j = begA + 64; j < endA; ++j) {     // deg>64 (rare)
        int s = srcs[j];
        float e = el2[s] + rdA;
        e = e > 0.f ? e : 0.2f * e;
        float ww = (half == 0) ? __expf(e) : 0.f;
        unsigned int u = act ? h2b32[(size_t)s * 20 + il] : 0u;
        float2 xv = bf2x(u);
        accA.x = fmaf(ww, xv.x, accA.x);
        accA.y = fmaf(ww, xv.y, accA.y);
    }
    for (int j = begB + 64; j < endB; ++j) {
        int s = srcs[j];
        float e = el2[s] + rdB;
        e = e > 0.f ? e : 0.2f * e;
        float ww = (half == 0) ? __expf(e) : 0.f;
        unsigned int u = act ? h2b32[(size_t)s * 20 + il] : 0u;
        float2 xv = bf2x(u);
        accB.x = fmaf(ww, xv.x, accB.x);
        accB.y = fmaf(ww, xv.y, accB.y);
    }
    // deferred: reduce dens over the full wave, after the loads
#pragma unroll
    for (int off = 32; off > 0; off >>= 1) {
        denA += __shfl_xor(denA, off);
        denB += __shfl_xor(denB, off);
    }
    float invA = denA > 0.f ? 1.f / denA : 0.f;
    float invB = denB > 0.f ? 1.f / denB : 0.f;
    accA.x += __shfl_xor(accA.x, 32);
    accA.y += __shfl_xor(accA.y, 32);
    accB.x += __shfl_xor(accB.x, 32);
    accB.y += __shfl_xor(accB.y, 32);
    if (half == 0 && act) {
        float2 bb = *(const float2*)&b2[2 * il];
        *(float2*)&out[(size_t)dA * NCLS + 2 * il] =
            make_float2(fmaf(accA.x, invA, bb.x), fmaf(accA.y, invA, bb.y));
        *(float2*)&out[(size_t)dB * NCLS + 2 * il] =
            make_float2(fmaf(accB.x, invB, bb.x), fmaf(accB.y, invB, bb.y));
    }
}

extern "C" void kernel_launch(void* const* d_in, const int* in_sizes, int n_in,
                              void* d_out, int out_size, void* d_ws, size_t ws_size,
                              hipStream_t stream) {
    const float* x   = (const float*)d_in[0];
    const int*   src = (const int*)d_in[1];
    const int*   dst = (const int*)d_in[2];
    const float* W1  = (const float*)d_in[3];
    const float* al1 = (const float*)d_in[4];
    const float* ar1 = (const float*)d_in[5];
    const float* b1  = (const float*)d_in[6];
    const float* W2  = (const float*)d_in[7];
    const float* al2 = (const float*)d_in[8];
    const float* ar2 = (const float*)d_in[9];
    const float* b2  = (const float*)d_in[10];
    float* out = (float*)d_out;

    float* ws = (float*)d_ws;
    size_t off = 0;
    unsigned short* xb    = (unsigned short*)(ws + off); off += (size_t)NN * 64;  // bf16 [N,128]
    unsigned short* h2b   = (unsigned short*)(ws + off); off += (size_t)NN * 20;  // bf16 [N,40]
    float* el1  = ws + off; off += (size_t)NN * 4;
    float* er1  = ws + off; off += (size_t)NN * 4;
    float* el2  = ws + off; off += NN;
    float* er2  = ws + off; off += NN;
    float* wel  = ws + off; off += 512;
    float* wer  = ws + off; off += 512;
    unsigned short* w1tb = (unsigned short*)(ws + off); off += 16384;             // bf16 [256,128]
    unsigned short* w2tb = (unsigned short*)(ws + off); off += 48 * 128;          // bf16 [48,256]
    float* w4   = ws + off; off += (size_t)NE * 4;                                // raw weights, CSR order
    int* counts = (int*)(ws + off);
    int* indptr = counts + NN;
    int* fill   = indptr + NN + 1;
    int* srcs   = fill + NN;
    int* bsum   = srcs + NE;
    int* dhist  = bsum + 256;
    int* dblk   = dhist + 256;          // [NB_SCAN][256]
    int* perm   = dblk + NB_SCAN * 256;

    const int NB = (NN + 255) / 256;    // == NB_SCAN

    k_prep<<<48, 256, 0, stream>>>(W1, al1, ar1, W2, wel, wer, w1tb, w2tb, counts);
    k_elr1x<<<(NN + 63) / 64, 256, 0, stream>>>(x, wel, wer, el1, er1, xb, dst, counts);
    k_scanA<<<NB, 256, 0, stream>>>(counts, indptr, bsum, dblk);
    k_scanB<<<1, 256, 0, stream>>>(bsum, NB, dblk, dhist);
    k_scanC<<<NB, 256, 0, stream>>>(indptr, bsum, fill, counts, dhist, dblk, perm);
    k_scatterw<<<(NE + 255) / 256, 256, 0, stream>>>(src, dst, indptr, fill,
                                                     el1, er1, srcs, (float4*)w4);
    k_agg1m<<<NN / 16, 256, 0, stream>>>((const unsigned int*)xb, (const float4*)w4,
                                         indptr, srcs, perm, w1tb, w2tb, b1, al2, ar2,
                                         h2b, el2, er2);

    k_agg2<<<NN / 8, 256, 0, stream>>>((const unsigned int*)h2b, el2, er2, b2,
                                       indptr, srcs, perm, out);
}

// Round 21
// 197.215 us; speedup vs baseline: 2.2674x; 1.0892x over previous
//
#include <hip/hip_runtime.h>

#define NN 50000
#define NE 800000
#define HID 256
#define NCLS 40

typedef short bf16x8 __attribute__((ext_vector_type(8)));
typedef float f32x4 __attribute__((ext_vector_type(4)));

__device__ inline unsigned short f2bf(float f) {            // RNE float->bf16
    unsigned int u = __float_as_uint(f);
    return (unsigned short)((u + 0x7FFFu + ((u >> 16) & 1u)) >> 16);
}
__device__ inline unsigned int pack2bf(float a, float b) {
    return (unsigned int)f2bf(a) | ((unsigned int)f2bf(b) << 16);
}
__device__ inline float2 bf2x(unsigned int u) {             // 2 bf16 -> 2 f32
    return make_float2(__uint_as_float(u << 16), __uint_as_float(u & 0xFFFF0000u));
}

// ---------------- CSR build ----------------
__global__ void k_scanA(const int* __restrict__ counts, int* __restrict__ indptr,
                        int* __restrict__ bsum) {
    __shared__ int sh[256];
    int t = threadIdx.x;
    int idx = blockIdx.x * 256 + t;
    int c = idx < NN ? counts[idx] : 0;
    sh[t] = c;
    __syncthreads();
    for (int off = 1; off < 256; off <<= 1) {
        int v = (t >= off) ? sh[t - off] : 0;
        __syncthreads();
        sh[t] += v;
        __syncthreads();
    }
    if (idx < NN) indptr[idx] = sh[t] - c;
    if (t == 255) bsum[blockIdx.x] = sh[255];
}

__global__ void k_scanB(int* __restrict__ bsum, int nb) {
    __shared__ int sh[256];
    int t = threadIdx.x;
    int c = t < nb ? bsum[t] : 0;
    sh[t] = c;
    __syncthreads();
    for (int off = 1; off < 256; off <<= 1) {
        int v = (t >= off) ? sh[t - off] : 0;
        __syncthreads();
        sh[t] += v;
        __syncthreads();
    }
    if (t < nb) bsum[t] = sh[t] - c;
}

__global__ void k_scanC(int* __restrict__ indptr, const int* __restrict__ bsum,
                        int* __restrict__ fill) {
    int idx = blockIdx.x * 256 + threadIdx.x;
    if (idx < NN) {
        indptr[idx] += bsum[idx >> 8];
        fill[idx] = 0;
    }
    if (idx == 0) indptr[NN] = NE;
}

// scatter + fused layer-1 edge weights (raw, unnormalized) in CSR order
__global__ void k_scatterw(const int* __restrict__ src, const int* __restrict__ dst,
                           const int* __restrict__ indptr, int* __restrict__ fill,
                           const float* __restrict__ el1, const float* __restrict__ er1,
                           int* __restrict__ srcs, float4* __restrict__ w4) {
    int e = blockIdx.x * 256 + threadIdx.x;
    if (e < NE) {
        int d = dst[e];
        int s = src[e];
        int pos = atomicAdd(&fill[d], 1);
        int j = indptr[d] + pos;
        srcs[j] = s;
        float4 ls = *(const float4*)&el1[(size_t)s * 4];
        float4 rd = *(const float4*)&er1[(size_t)d * 4];
        float e0 = ls.x + rd.x, e1 = ls.y + rd.y, e2 = ls.z + rd.z, e3 = ls.w + rd.w;
        e0 = e0 > 0.f ? e0 : 0.2f * e0;
        e1 = e1 > 0.f ? e1 : 0.2f * e1;
        e2 = e2 > 0.f ? e2 : 0.2f * e2;
        e3 = e3 > 0.f ? e3 : 0.2f * e3;
        w4[j] = make_float4(__expf(e0), __expf(e1), __expf(e2), __expf(e3));
    }
}

// ---------------- precompute: wel/wer + W1^T(bf16) + W2^T(bf16) + zero counts ----------
__global__ void k_prep(const float* __restrict__ W1, const float* __restrict__ al,
                       const float* __restrict__ ar, const float* __restrict__ W2,
                       float* __restrict__ wel, float* __restrict__ wer,
                       unsigned short* __restrict__ W1Tb,
                       unsigned short* __restrict__ W2Tb,
                       int* __restrict__ counts) {
    int gid = blockIdx.x * 256 + threadIdx.x;
    int nth = gridDim.x * 256;
    const int TOT = 512 + 32768 + 48 * 256;
    for (int i = gid; i < TOT; i += nth) {
        if (i < 512) {
            int k = i >> 2, h = i & 3;
            float a = 0.f, b = 0.f;
            for (int dd = 0; dd < 64; ++dd) {
                float w = W1[k * 256 + h * 64 + dd];
                a = fmaf(w, al[h * 64 + dd], a);
                b = fmaf(w, ar[h * 64 + dd], b);
            }
            wel[i] = a;            // i == k*4+h
            wer[i] = b;
        } else if (i < 512 + 32768) {
            int j = i - 512;
            int col = j >> 7, k = j & 127;
            W1Tb[j] = f2bf(W1[k * 256 + col]);      // W1T [256 cols][128 k] bf16
        } else {
            int j = i - 512 - 32768;
            int col = j >> 8, kk = j & 255;         // [48 cols][256 k]
            W2Tb[j] = (col < NCLS) ? f2bf(W2[kk * 40 + col]) : (unsigned short)0;
        }
    }
    for (int i = gid; i < NN; i += nth) counts[i] = 0;
}

// el1/er1[N,4] = x @ wel / x @ wer ; bf16 copy of x ; fused edge-count pass
__global__ void k_elr1x(const float* __restrict__ x, const float* __restrict__ wel,
                        const float* __restrict__ wer, float* __restrict__ el1,
                        float* __restrict__ er1, unsigned short* __restrict__ xb,
                        const int* __restrict__ dst, int* __restrict__ counts) {
    __shared__ float xs[64 * 129];
    __shared__ float wels[512], wers[512];
    int t = threadIdx.x;
    int n0 = blockIdx.x * 64;
    wels[t] = wel[t]; wels[256 + t] = wel[256 + t];
    wers[t] = wer[t]; wers[256 + t] = wer[256 + t];
    for (int i = 0; i < 8; ++i) {
        int f = i * 256 + t;
        int row = f >> 5;
        int col4 = (f & 31) * 4;
        float4 v = make_float4(0.f, 0.f, 0.f, 0.f);
        if (n0 + row < NN) v = ((const float4*)x)[(size_t)n0 * 32 + f];
        xs[row * 129 + col4 + 0] = v.x;
        xs[row * 129 + col4 + 1] = v.y;
        xs[row * 129 + col4 + 2] = v.z;
        xs[row * 129 + col4 + 3] = v.w;
    }
    __syncthreads();
    int node = t & 63;
    int h = t >> 6;
    float a = 0.f, b = 0.f;
    for (int k = 0; k < 128; ++k) {
        float xv = xs[node * 129 + k];
        a = fmaf(xv, wels[k * 4 + h], a);
        b = fmaf(xv, wers[k * 4 + h], b);
    }
    if (n0 + node < NN) {
        el1[(size_t)(n0 + node) * 4 + h] = a;
        er1[(size_t)(n0 + node) * 4 + h] = b;
    }
    for (int i = 0; i < 4; ++i) {
        int g = (i * 256 + t) * 8;
        int row = g >> 7, col = g & 127;
        if (n0 + row < NN) {
            ushort4 lo, hi;
            lo.x = f2bf(xs[row * 129 + col + 0]);
            lo.y = f2bf(xs[row * 129 + col + 1]);
            lo.z = f2bf(xs[row * 129 + col + 2]);
            lo.w = f2bf(xs[row * 129 + col + 3]);
            hi.x = f2bf(xs[row * 129 + col + 4]);
            hi.y = f2bf(xs[row * 129 + col + 5]);
            hi.z = f2bf(xs[row * 129 + col + 6]);
            hi.w = f2bf(xs[row * 129 + col + 7]);
            *(ushort4*)&xb[(size_t)(n0 + row) * 128 + col] = lo;
            *(ushort4*)&xb[(size_t)(n0 + row) * 128 + col + 4] = hi;
        }
    }
    // fused degree count (independent edge pass; overlaps with other blocks' compute)
    int gid = blockIdx.x * 256 + t;
    int nth = gridDim.x * 256;
    for (int e = gid; e < NE; e += nth) atomicAdd(&counts[dst[e]], 1);
}

// ---------------- fused layer-1+2a: gather(MLP16) -> MFMA@W1 -> ELU(LDS) -> MFMA@W2 ----
// 256 thr / 4 waves / 16 dsts per block (round-14/16/18 geometry, best measured).
#define XG_STRIDE 260      // uints per node (256 + 4 pad)
#define EB_STRIDE 264      // ushorts per node row (256 + 8 pad), 16B-aligned stride
#define FMA8(AC0, AC1, AC2, AC3, WQ, XV) \
    AC0.x = fmaf(WQ.x, XV.x, AC0.x); AC0.y = fmaf(WQ.x, XV.y, AC0.y); \
    AC1.x = fmaf(WQ.y, XV.x, AC1.x); AC1.y = fmaf(WQ.y, XV.y, AC1.y); \
    AC2.x = fmaf(WQ.z, XV.x, AC2.x); AC2.y = fmaf(WQ.z, XV.y, AC2.y); \
    AC3.x = fmaf(WQ.w, XV.x, AC3.x); AC3.y = fmaf(WQ.w, XV.y, AC3.y);

__global__ void k_agg1m(const unsigned int* __restrict__ xb32,
                        const float4* __restrict__ w4,
                        const int* __restrict__ indptr, const int* __restrict__ srcs,
                        const unsigned short* __restrict__ W1Tb,
                        const unsigned short* __restrict__ W2Tb,
                        const float* __restrict__ b1,
                        const float* __restrict__ al2, const float* __restrict__ ar2,
                        unsigned short* __restrict__ h2b,
                        float* __restrict__ el2, float* __restrict__ er2) {
    __shared__ unsigned int xg[16 * XG_STRIDE];            // 16.6 KB
    __shared__ __align__(16) unsigned char pool[10496];    // sw+si, later eb+pel/per
    float4 (*sw)[64] = (float4(*)[64])pool;                // 8 KB
    int (*si)[64] = (int(*)[64])(pool + 8192);             // 2 KB
    unsigned short* eb = (unsigned short*)pool;            // [16][EB_STRIDE] = 8448 B
    float* pel = (float*)(pool + 8448);                    // [3][16]
    float* per_ = (float*)(pool + 8640);                   // [3][16]
    int t = threadIdx.x;
    int wv = t >> 6, l = t & 63;
    int n0 = blockIdx.x * 16;
    int d0 = n0 + wv * 4;
    int ip[5];
#pragma unroll
    for (int q = 0; q < 5; ++q) ip[q] = indptr[d0 + q];
    int w2 = wv * 2;
#pragma unroll
    for (int p = 0; p < 2; ++p) {
        int begA = ip[2 * p + 0], endA = ip[2 * p + 1];
        int begB = ip[2 * p + 1], endB = ip[2 * p + 2];
        int degA = endA - begA, degB = endB - begB;
        // ---- coalesced weight+index load (raw weights from scatterw) ----
        int sA = 0, sB = 0;
        float4 wA = make_float4(0.f, 0.f, 0.f, 0.f);
        float4 wB = make_float4(0.f, 0.f, 0.f, 0.f);
        if (l < degA) { sA = srcs[begA + l]; wA = w4[begA + l]; }
        if (l < degB) { sB = srcs[begB + l]; wB = w4[begB + l]; }
        si[w2 + 0][l] = sA; sw[w2 + 0][l] = wA;
        si[w2 + 1][l] = sB; sw[w2 + 1][l] = wB;
        // ---- interleaved gather: up to 16 rows in flight ----
        float2 aA0 = {0,0}, aA1 = {0,0}, aA2 = {0,0}, aA3 = {0,0};
        float2 aB0 = {0,0}, aB1 = {0,0}, aB2 = {0,0}, aB3 = {0,0};
        int capA = degA < 64 ? degA : 64;
        int capB = degB < 64 ? degB : 64;
        int mcap = capA > capB ? capA : capB;
        for (int e = 0; e < mcap; e += 8) {
            unsigned int uA[8], uB[8];
            bool doA = e < capA, doB = e < capB;
            if (doA) {
#pragma unroll
                for (int q = 0; q < 8; ++q)
                    uA[q] = xb32[(size_t)si[w2][e + q] * 64 + l];
            }
            if (doB) {
#pragma unroll
                for (int q = 0; q < 8; ++q)
                    uB[q] = xb32[(size_t)si[w2 + 1][e + q] * 64 + l];
            }
            if (doA) {
#pragma unroll
                for (int q = 0; q < 8; ++q) {
                    float4 wq = sw[w2][e + q];
                    float2 xv = bf2x(uA[q]);
                    FMA8(aA0, aA1, aA2, aA3, wq, xv)
                }
            }
            if (doB) {
#pragma unroll
                for (int q = 0; q < 8; ++q) {
                    float4 wq = sw[w2 + 1][e + q];
                    float2 xv = bf2x(uB[q]);
                    FMA8(aB0, aB1, aB2, aB3, wq, xv)
                }
            }
        }
        // ---- deg>64 tails (rare) ----
        for (int j = begA + 64; j < endA; ++j) {
            float4 wq = w4[j];
            float2 xv = bf2x(xb32[(size_t)srcs[j] * 64 + l]);
            FMA8(aA0, aA1, aA2, aA3, wq, xv)
        }
        for (int j = begB + 64; j < endB; ++j) {
            float4 wq = w4[j];
            float2 xv = bf2x(xb32[(size_t)srcs[j] * 64 + l]);
            FMA8(aB0, aB1, aB2, aB3, wq, xv)
        }
        // ---- denominators (deferred) ----
        float dA0 = wA.x, dA1 = wA.y, dA2 = wA.z, dA3 = wA.w;
        float dB0 = wB.x, dB1 = wB.y, dB2 = wB.z, dB3 = wB.w;
        for (int j = begA + 64 + l; j < endA; j += 64) {
            float4 wt = w4[j];
            dA0 += wt.x; dA1 += wt.y; dA2 += wt.z; dA3 += wt.w;
        }
        for (int j = begB + 64 + l; j < endB; j += 64) {
            float4 wt = w4[j];
            dB0 += wt.x; dB1 += wt.y; dB2 += wt.z; dB3 += wt.w;
        }
#pragma unroll
        for (int off = 32; off > 0; off >>= 1) {
            dA0 += __shfl_xor(dA0, off); dA1 += __shfl_xor(dA1, off);
            dA2 += __shfl_xor(dA2, off); dA3 += __shfl_xor(dA3, off);
            dB0 += __shfl_xor(dB0, off); dB1 += __shfl_xor(dB1, off);
            dB2 += __shfl_xor(dB2, off); dB3 += __shfl_xor(dB3, off);
        }
        float iA0 = dA0 > 0.f ? 1.f / dA0 : 0.f;
        float iA1 = dA1 > 0.f ? 1.f / dA1 : 0.f;
        float iA2 = dA2 > 0.f ? 1.f / dA2 : 0.f;
        float iA3 = dA3 > 0.f ? 1.f / dA3 : 0.f;
        float iB0 = dB0 > 0.f ? 1.f / dB0 : 0.f;
        float iB1 = dB1 > 0.f ? 1.f / dB1 : 0.f;
        float iB2 = dB2 > 0.f ? 1.f / dB2 : 0.f;
        float iB3 = dB3 > 0.f ? 1.f / dB3 : 0.f;
        unsigned int* xgA = &xg[(wv * 4 + 2 * p + 0) * XG_STRIDE];
        xgA[0 * 64 + l] = pack2bf(aA0.x * iA0, aA0.y * iA0);
        xgA[1 * 64 + l] = pack2bf(aA1.x * iA1, aA1.y * iA1);
        xgA[2 * 64 + l] = pack2bf(aA2.x * iA2, aA2.y * iA2);
        xgA[3 * 64 + l] = pack2bf(aA3.x * iA3, aA3.y * iA3);
        unsigned int* xgB = &xg[(wv * 4 + 2 * p + 1) * XG_STRIDE];
        xgB[0 * 64 + l] = pack2bf(aB0.x * iB0, aB0.y * iB0);
        xgB[1 * 64 + l] = pack2bf(aB1.x * iB1, aB1.y * iB1);
        xgB[2 * 64 + l] = pack2bf(aB2.x * iB2, aB2.y * iB2);
        xgB[3 * 64 + l] = pack2bf(aB3.x * iB3, aB3.y * iB3);
    }
    __syncthreads();                 // xg ready; pool (si/sw) dead after this point
    // ---- MFMA1: wave wv = head wv; 16 nodes x 64 cols, K=128; ELU -> eb (LDS) ----
    int lrow = l & 15, lk = l >> 4;
    {
        f32x4 acc[4] = {};
#pragma unroll
        for (int kt = 0; kt < 4; ++kt) {
            bf16x8 av = *(const bf16x8*)&xg[lrow * XG_STRIDE + wv * 64 + kt * 16 + lk * 4];
#pragma unroll
            for (int nt = 0; nt < 4; ++nt) {
                int col = wv * 64 + nt * 16 + lrow;
                bf16x8 bv = *(const bf16x8*)&W1Tb[(size_t)col * 128 + kt * 32 + lk * 8];
                acc[nt] = __builtin_amdgcn_mfma_f32_16x16x32_bf16(av, bv, acc[nt], 0, 0, 0);
            }
        }
#pragma unroll
        for (int nt = 0; nt < 4; ++nt) {
            int col = wv * 64 + nt * 16 + lrow;
            float bv1 = b1[col];
#pragma unroll
            for (int r = 0; r < 4; ++r) {
                int rloc = lk * 4 + r;
                float o = acc[nt][r] + bv1;
                o = o > 0.f ? o : (__expf(o) - 1.f);
                eb[rloc * EB_STRIDE + col] = f2bf(o);
            }
        }
    }
    __syncthreads();                 // eb ready
    // ---- MFMA2: waves 0..2 compute col tiles 0..2 of [16,256]@[256,48] ----
    if (wv < 3) {
        f32x4 acc2 = {};
#pragma unroll
        for (int kt = 0; kt < 8; ++kt) {
            bf16x8 av = *(const bf16x8*)&eb[lrow * EB_STRIDE + kt * 32 + lk * 8];
            bf16x8 bv = *(const bf16x8*)&W2Tb[(size_t)(wv * 16 + lrow) * 256 + kt * 32 + lk * 8];
            acc2 = __builtin_amdgcn_mfma_f32_16x16x32_bf16(av, bv, acc2, 0, 0, 0);
        }
        int col2 = wv * 16 + lrow;
        float alc = col2 < NCLS ? al2[col2] : 0.f;
        float arc = col2 < NCLS ? ar2[col2] : 0.f;
#pragma unroll
        for (int r = 0; r < 4; ++r) {
            int row = n0 + lk * 4 + r;
            float v = acc2[r];
            if (col2 < NCLS) h2b[(size_t)row * NCLS + col2] = f2bf(v);
            float pa = v * alc, pb = v * arc;
#pragma unroll
            for (int off = 1; off < 16; off <<= 1) {
                pa += __shfl_xor(pa, off);
                pb += __shfl_xor(pb, off);
            }
            if (lrow == 0) {
                pel[wv * 16 + lk * 4 + r] = pa;
                per_[wv * 16 + lk * 4 + r] = pb;
            }
        }
    }
    __syncthreads();
    if (t < 16) {
        el2[n0 + t] = pel[t] + pel[16 + t] + pel[32 + t];
        er2[n0 + t] = per_[t] + per_[16 + t] + per_[32 + t];
    }
}

// merged layer-2 softmax + aggregation: 2 dsts per wave, half-wave split, MLP16
__global__ void k_agg2(const unsigned int* __restrict__ h2b32,
                       const float* __restrict__ el2,
                       const float* __restrict__ er2, const float* __restrict__ b2,
                       const int* __restrict__ indptr, const int* __restrict__ srcs,
                       float* __restrict__ out) {
    __shared__ int   si[8][64];
    __shared__ float sw[8][64];
    int t = threadIdx.x;
    int wv = t >> 6, l = t & 63;
    int dA = blockIdx.x * 8 + wv * 2;
    int dB = dA + 1;
    int begA = indptr[dA], endA = indptr[dA + 1];
    int begB = endA, endB = indptr[dB + 1];
    int degA = endA - begA, degB = endB - begB;
    float rdA = er2[dA], rdB = er2[dB];
    int sA = 0, sB = 0;
    float wA = 0.f, wB = 0.f;
    if (l < degA) {
        sA = srcs[begA + l];
        float e = el2[sA] + rdA;
        e = e > 0.f ? e : 0.2f * e;
        wA = __expf(e);
    }
    if (l < degB) {
        sB = srcs[begB + l];
        float e = el2[sB] + rdB;
        e = e > 0.f ? e : 0.2f * e;
        wB = __expf(e);
    }
    int w2 = wv * 2;
    si[w2 + 0][l] = sA; sw[w2 + 0][l] = wA;
    si[w2 + 1][l] = sB; sw[w2 + 1][l] = wB;
    float denA = wA, denB = wB;
    for (int j = begA + 64 + l; j < endA; j += 64) {
        float e = el2[srcs[j]] + rdA;
        e = e > 0.f ? e : 0.2f * e;
        denA += __expf(e);
    }
    for (int j = begB + 64 + l; j < endB; j += 64) {
        float e = el2[srcs[j]] + rdB;
        e = e > 0.f ? e : 0.2f * e;
        denB += __expf(e);
    }
    // payload: half-wave edge split; lane il holds cols {2*il, 2*il+1}
    int half = l >> 5, il = l & 31;
    bool act = il < 20;
    float2 accA = {0.f, 0.f}, accB = {0.f, 0.f};
    int capA = degA < 64 ? degA : 64;
    int capB = degB < 64 ? degB : 64;
    int mcap = capA > capB ? capA : capB;
    for (int e = 0; e < mcap; e += 8) {
        bool doA = e < capA, doB = e < capB;
        int ixA[4], ixB[4];
        float wsA[4], wsB[4];
        unsigned int uA[4], uB[4];
        if (doA) {
#pragma unroll
            for (int q = 0; q < 4; ++q) {
                int idx = e + 2 * q + half;
                ixA[q] = si[w2][idx];
                wsA[q] = sw[w2][idx];
            }
        }
        if (doB) {
#pragma unroll
            for (int q = 0; q < 4; ++q) {
                int idx = e + 2 * q + half;
                ixB[q] = si[w2 + 1][idx];
                wsB[q] = sw[w2 + 1][idx];
            }
        }
        if (doA) {
#pragma unroll
            for (int q = 0; q < 4; ++q)
                uA[q] = act ? h2b32[(size_t)ixA[q] * 20 + il] : 0u;
        }
        if (doB) {
#pragma unroll
            for (int q = 0; q < 4; ++q)
                uB[q] = act ? h2b32[(size_t)ixB[q] * 20 + il] : 0u;
        }
        if (doA) {
#pragma unroll
            for (int q = 0; q < 4; ++q) {
                float2 xv = bf2x(uA[q]);
                accA.x = fmaf(wsA[q], xv.x, accA.x);
                accA.y = fmaf(wsA[q], xv.y, accA.y);
            }
        }
        if (doB) {
#pragma unroll
            for (int q = 0; q < 4; ++q) {
                float2 xv = bf2x(uB[q]);
                accB.x = fmaf(wsB[q], xv.x, accB.x);
                accB.y = fmaf(wsB[q], xv.y, accB.y);
            }
        }
    }
    for (int j = begA + 64; j < endA; ++j) {     // deg>64 (rare)
        int s = srcs[j];
        float e = el2[s] + rdA;
        e = e > 0.f ? e : 0.2f * e;
        float ww = (half == 0) ? __expf(e) : 0.f;
        unsigned int u = act ? h2b32[(size_t)s * 20 + il] : 0u;
        float2 xv = bf2x(u);
        accA.x = fmaf(ww, xv.x, accA.x);
        accA.y = fmaf(ww, xv.y, accA.y);
    }
    for (int j = begB + 64; j < endB; ++j) {
        int s = srcs[j];
        float e = el2[s] + rdB;
        e = e > 0.f ? e : 0.2f * e;
        float ww = (half == 0) ? __expf(e) : 0.f;
        unsigned int u = act ? h2b32[(size_t)s * 20 + il] : 0u;
        float2 xv = bf2x(u);
        accB.x = fmaf(ww, xv.x, accB.x);
        accB.y = fmaf(ww, xv.y, accB.y);
    }
    // deferred: reduce dens over the full wave, after the loads
#pragma unroll
    for (int off = 32; off > 0; off >>= 1) {
        denA += __shfl_xor(denA, off);
        denB += __shfl_xor(denB, off);
    }
    float invA = denA > 0.f ? 1.f / denA : 0.f;
    float invB = denB > 0.f ? 1.f / denB : 0.f;
    accA.x += __shfl_xor(accA.x, 32);
    accA.y += __shfl_xor(accA.y, 32);
    accB.x += __shfl_xor(accB.x, 32);
    accB.y += __shfl_xor(accB.y, 32);
    if (half == 0 && act) {
        float2 bb = *(const float2*)&b2[2 * il];
        *(float2*)&out[(size_t)dA * NCLS + 2 * il] =
            make_float2(fmaf(accA.x, invA, bb.x), fmaf(accA.y, invA, bb.y));
        *(float2*)&out[(size_t)dB * NCLS + 2 * il] =
            make_float2(fmaf(accB.x, invB, bb.x), fmaf(accB.y, invB, bb.y));
    }
}

extern "C" void kernel_launch(void* const* d_in, const int* in_sizes, int n_in,
                              void* d_out, int out_size, void* d_ws, size_t ws_size,
                              hipStream_t stream) {
    const float* x   = (const float*)d_in[0];
    const int*   src = (const int*)d_in[1];
    const int*   dst = (const int*)d_in[2];
    const float* W1  = (const float*)d_in[3];
    const float* al1 = (const float*)d_in[4];
    const float* ar1 = (const float*)d_in[5];
    const float* b1  = (const float*)d_in[6];
    const float* W2  = (const float*)d_in[7];
    const float* al2 = (const float*)d_in[8];
    const float* ar2 = (const float*)d_in[9];
    const float* b2  = (const float*)d_in[10];
    float* out = (float*)d_out;

    float* ws = (float*)d_ws;
    size_t off = 0;
    unsigned short* xb    = (unsigned short*)(ws + off); off += (size_t)NN * 64;  // bf16 [N,128]
    unsigned short* h2b   = (unsigned short*)(ws + off); off += (size_t)NN * 20;  // bf16 [N,40]
    float* el1  = ws + off; off += (size_t)NN * 4;
    float* er1  = ws + off; off += (size_t)NN * 4;
    float* el2  = ws + off; off += NN;
    float* er2  = ws + off; off += NN;
    float* wel  = ws + off; off += 512;
    float* wer  = ws + off; off += 512;
    unsigned short* w1tb = (unsigned short*)(ws + off); off += 16384;             // bf16 [256,128]
    unsigned short* w2tb = (unsigned short*)(ws + off); off += 48 * 128;          // bf16 [48,256]
    float* w4   = ws + off; off += (size_t)NE * 4;                                // raw weights, CSR order
    int* counts = (int*)(ws + off);
    int* indptr = counts + NN;
    int* fill   = indptr + NN + 1;
    int* srcs   = fill + NN;
    int* bsum   = srcs + NE;

    const int NB = (NN + 255) / 256;

    k_prep<<<48, 256, 0, stream>>>(W1, al1, ar1, W2, wel, wer, w1tb, w2tb, counts);
    k_elr1x<<<(NN + 63) / 64, 256, 0, stream>>>(x, wel, wer, el1, er1, xb, dst, counts);
    k_scanA<<<NB, 256, 0, stream>>>(counts, indptr, bsum);
    k_scanB<<<1, 256, 0, stream>>>(bsum, NB);
    k_scanC<<<NB, 256, 0, stream>>>(indptr, bsum, fill);
    k_scatterw<<<(NE + 255) / 256, 256, 0, stream>>>(src, dst, indptr, fill,
                                                     el1, er1, srcs, (float4*)w4);
    k_agg1m<<<NN / 16, 256, 0, stream>>>((const unsigned int*)xb, (const float4*)w4,
                                         indptr, srcs, w1tb, w2tb, b1, al2, ar2,
                                         h2b, el2, er2);

    k_agg2<<<NN / 8, 256, 0, stream>>>((const unsigned int*)h2b, el2, er2, b2,
                                       indptr, srcs, out);
}